// Round 9
// baseline (71.375 us; speedup 1.0000x reference)
//
#include <hip/hip_runtime.h>
#include <stdint.h>

#define NBOX 6400
#define GRIDW 80
#define NC 20
#define NBLK 100        // NBOX / 64
#define WIN 8           // window half-width in chunks: test b-8..b+8 exactly
#define NWCH 17         // 2*WIN+1
// Pairs with chunk distance >=9 force gx distance >=5 => x center gap >=128px
// => some raw w > 128px => tw > ln(128)=4.852. Conservative threshold:
#define TWMAX 4.85f

__device__ __forceinline__ float sigmoidf(float x) { return 1.0f / (1.0f + expf(-x)); }
__device__ __forceinline__ float clip01(float x) { return fminf(fmaxf(x, 0.0f), 1.0f); }

// Exact reference decode (outputs must be bit-faithful).
__device__ __forceinline__ void decode_full(const float* __restrict__ p, int n,
        float4* box, float* score, int* cls) {
    float conf = sigmoidf(p[0]);
    float c[NC];
    float m = -INFINITY;
    #pragma unroll
    for (int j = 0; j < NC; j++) { c[j] = p[1 + j]; m = fmaxf(m, c[j]); }
    float sum = 0.f;
    #pragma unroll
    for (int j = 0; j < NC; j++) { c[j] = expf(c[j] - m); sum += c[j]; }
    float best = -INFINITY; int bi = 0;
    #pragma unroll
    for (int j = 0; j < NC; j++) {
        float s = (c[j] / sum) * conf;        // softmax*conf, first-max argmax
        if (s > best) { best = s; bi = j; }
    }
    float gx = (float)(n / GRIDW), gy = (float)(n % GRIDW);
    float cx = (gx + sigmoidf(p[21])) * 32.0f;
    float cy = (gy + sigmoidf(p[22])) * 32.0f;
    float w = expf(p[23]), h = expf(p[24]);
    box->x = clip01((cx - w * 0.5f) / 2560.0f);
    box->y = clip01((cy - h * 0.5f) / 2560.0f);
    box->z = clip01((cx + w * 0.5f) / 2560.0f);
    box->w = clip01((cy + h * 0.5f) / 2560.0f);
    *score = best;
    *cls = bi;
}

// Cheap screen decode: geometry + logit-argmax class (same argmax as softmax*conf
// since softmax is monotone; used ONLY for the conservative pair screen, computed
// with identical FP ops by every block -> identical verdicts everywhere).
__device__ __forceinline__ void decode_screen(const float* __restrict__ p, int n,
        float4* obox, float* ux1, float* ux2) {
    float bestl = -INFINITY; int cls = 0;
    #pragma unroll
    for (int j = 0; j < NC; j++) { float v = p[1 + j]; if (v > bestl) { bestl = v; cls = j; } }
    float gx = (float)(n / GRIDW), gy = (float)(n % GRIDW);
    float cx = (gx + sigmoidf(p[21])) * 32.0f;
    float cy = (gy + sigmoidf(p[22])) * 32.0f;
    float w = expf(p[23]), h = expf(p[24]);
    float x1 = clip01((cx - w * 0.5f) / 2560.0f);
    float y1 = clip01((cy - h * 0.5f) / 2560.0f);
    float x2 = clip01((cx + w * 0.5f) / 2560.0f);
    float y2 = clip01((cy + h * 0.5f) / 2560.0f);
    float off = 2.0f * (float)cls;            // class-offset trick
    *obox = make_float4(x1 + off, y1 + off, x2 + off, y2 + off);
    *ux1 = x1; *ux2 = x2;                     // un-offset x-range (chunk screen)
}

// Single dispatch, 100 blocks x 256. NO cross-block communication at all.
// Block b: (1) global tw scan (far-pair reach bound); (2) screen-decode chunks
// b-8..b+8 to LDS; (3) conservative pair test (x-range chunk skip + div-free
// IoU>0.5); (4) clean -> write own keep/scores (exact: no suppressing pair
// anywhere). Hit -> self-contained exact NMS re-decoded from pred (identical
// result from every triggered block; racing writes are byte-identical).
__global__ __launch_bounds__(256) void k_one(const float* __restrict__ pred,
        float* __restrict__ out, float4* __restrict__ boffw, int* __restrict__ sidx,
        float* __restrict__ sscore, float4* __restrict__ sbox) {
    __shared__ float4 bl[NWCH * 64];       // 17.4 KB offset screen boxes
    __shared__ float2 xr[NWCH];            // un-offset x-range per window chunk
    __shared__ float sc64[64];             // own chunk exact scores
    __shared__ float wmaxsh[4];
    __shared__ uint32_t whit[4];
    __shared__ uint64_t klds[NBOX];        // 51.2 KB, fallback only
    __shared__ uint32_t keepb[NBOX / 32];  // fallback only
    int t = threadIdx.x, w = t >> 6, l = t & 63, b = blockIdx.x;

    // ---- (1) global raw-width scan: any tw > ln(128)? ----
    float twmax = -1e30f;
    #pragma unroll 5
    for (int k = 0; k < 25; k++) twmax = fmaxf(twmax, pred[(size_t)(t + 256 * k) * 25 + 23]);
    #pragma unroll
    for (int d = 1; d < 64; d <<= 1) twmax = fmaxf(twmax, __shfl_xor(twmax, d));
    if (l == 0) wmaxsh[w] = twmax;

    // ---- (2) screen-decode 17 chunks; per-(wave,iter) = one chunk x-range ----
    for (int k = 0; k < 5; k++) {
        int m = 256 * k + t;
        if (m < NWCH * 64) {               // wave-uniform guard
            int wc = m >> 6;
            int cblk = b - WIN + wc;
            float4 ob = make_float4(-1e6f, -1e6f, -1e6f, -1e6f);
            float ux1 = 1e30f, ux2 = -1e30f;
            if (cblk >= 0 && cblk < NBLK)
                decode_screen(pred + (size_t)(cblk * 64 + (m & 63)) * 25,
                              cblk * 64 + (m & 63), &ob, &ux1, &ux2);
            bl[m] = ob;
            #pragma unroll
            for (int d = 1; d < 64; d <<= 1) {
                ux1 = fminf(ux1, __shfl_xor(ux1, d));
                ux2 = fmaxf(ux2, __shfl_xor(ux2, d));
            }
            if ((m & 63) == 0) xr[wc] = make_float2(ux1, ux2);
        }
    }
    // ---- own chunk full decode: boxes/class now, keep/scores deferred ----
    if (t < 64) {
        int n = b * 64 + t;
        float4 bx; float s; int cls;
        decode_full(pred + (size_t)n * 25, n, &bx, &s, &cls);
        ((float4*)out)[n] = bx;            // output 0: boxes
        out[32000 + n] = (float)cls;       // output 2: class_idx
        sc64[t] = s;
    }
    __syncthreads();

    // ---- (3) conservative pair test ----
    float4 rb = bl[WIN * 64 + l];
    float areai = (rb.z - rb.x) * (rb.w - rb.y);
    float2 xro = xr[WIN];
    bool hit = (fmaxf(fmaxf(wmaxsh[0], wmaxsh[1]), fmaxf(wmaxsh[2], wmaxsh[3])) > TWMAX);
    for (int c = 0; c < NWCH; c++) {       // uniform chunk loop
        float2 xc = xr[c];
        // same-class needed for a hit (offsets separate classes by >=1) =>
        // un-offset x-range disjoint => no pair possible with this chunk
        if (fminf(xro.y, xc.y) + 1e-6f < fmaxf(xro.x, xc.x)) continue;
        #pragma unroll
        for (int k2 = 0; k2 < 16; k2++) {
            int s2 = w * 16 + k2;          // wave-uniform column
            float4 bb = bl[c * 64 + s2];   // LDS broadcast read
            bool ok = !(c == WIN && s2 <= l);   // own chunk: unordered once
            float xx1 = fmaxf(rb.x, bb.x);
            float yy1 = fmaxf(rb.y, bb.y);
            float xx2 = fminf(rb.z, bb.z);
            float yy2 = fminf(rb.w, bb.w);
            float ww = fmaxf(1e-28f, xx2 - xx1);   // EPS exactly as reference
            float hh = fmaxf(1e-28f, yy2 - yy1);
            float inter = ww * hh;
            float areaj = (bb.z - bb.x) * (bb.w - bb.y);
            // iou>0.5 <=> 3*inter > A+B (denom>0); margin covers f32 rounding;
            // also fires on degenerate denom<=0 corners. Conservative superset.
            hit |= ok && (3.0f * inter >= 0.9995f * (areai + areaj));
        }
    }
    whit[w] = (__ballot(hit) != 0ull) ? 1u : 0u;
    __syncthreads();
    uint32_t H = whit[0] | whit[1] | whit[2] | whit[3];
    if (!H) {
        // ---- (4) clean: keep == valid is exact for this chunk ----
        if (t < 64) {
            int n = b * 64 + t;
            float s = sc64[t];
            bool valid = s >= 0.01f;
            out[25600 + n] = valid ? s : 0.0f;   // output 1: scores*keep
            out[38400 + n] = valid ? 1.0f : 0.0f;// output 3: keep
        }
        return;
    }

    // ---- fallback: self-contained exact reference NMS (re-decode from pred).
    // Deterministic: every triggered block writes identical bytes. ----
    for (int n = t; n < NBOX; n += 256) {
        float4 bx; float s; int cls;
        decode_full(pred + (size_t)n * 25, n, &bx, &s, &cls);
        float off = 2.0f * (float)cls;
        boffw[n] = make_float4(bx.x + off, bx.y + off, bx.z + off, bx.w + off);
        klds[n] = (((uint64_t)(~__float_as_uint(s))) << 32) | (uint32_t)n;
    }
    __syncthreads();
    for (int n = t; n < NBOX; n += 256) {  // rank sort (keys unique)
        uint64_t mk = klds[n];
        int r = 0;
        for (int j = 0; j < NBOX; j++) r += (klds[j] < mk) ? 1 : 0;
        sidx[r] = n;
        sscore[r] = __uint_as_float(~(uint32_t)(mk >> 32));
        sbox[r] = boffw[n];
    }
    __syncthreads();
    for (int w2 = t; w2 < NBOX / 32; w2 += 256) {
        uint32_t v = 0;
        for (int bb2 = 0; bb2 < 32; bb2++)
            v |= (sscore[w2 * 32 + bb2] >= 0.01f) ? (1u << bb2) : 0u;
        keepb[w2] = v;
    }
    __syncthreads();
    for (int ii = 0; ii < NBOX; ii++) {    // exact sequential greedy
        bool kept = (keepb[ii >> 5] >> (ii & 31)) & 1u;
        if (kept) {
            float4 a = sbox[ii];
            float areaa = (a.z - a.x) * (a.w - a.y);
            for (int j = ii + 1 + t; j < NBOX; j += 256) {
                if ((keepb[j >> 5] >> (j & 31)) & 1u) {
                    float4 bb = sbox[j];
                    float xx1 = fmaxf(a.x, bb.x);
                    float yy1 = fmaxf(a.y, bb.y);
                    float xx2 = fminf(a.z, bb.z);
                    float yy2 = fminf(a.w, bb.w);
                    float ww = fmaxf(1e-28f, xx2 - xx1);
                    float hh = fmaxf(1e-28f, yy2 - yy1);
                    float inter = ww * hh;
                    float areab = (bb.z - bb.x) * (bb.w - bb.y);
                    float iou = inter / (areaa + areab - inter);  // exact ref formula
                    if (iou > 0.5f) atomicAnd(&keepb[j >> 5], ~(1u << (j & 31)));
                }
            }
        }
        __syncthreads();
    }
    for (int r = t; r < NBOX; r += 256) {
        int orig = sidx[r];
        uint32_t kb = (keepb[r >> 5] >> (r & 31)) & 1u;
        out[38400 + orig] = (float)kb;
        out[25600 + orig] = kb ? sscore[r] : 0.0f;
    }
}

extern "C" void kernel_launch(void* const* d_in, const int* in_sizes, int n_in,
                              void* d_out, int out_size, void* d_ws, size_t ws_size,
                              hipStream_t stream) {
    const float* pred = (const float*)d_in[0];
    float* out = (float*)d_out;
    char* ws = (char*)d_ws;
    float4* boffw  = (float4*)(ws + 0);       // fallback scratch only
    int*    sidx   = (int*)(ws + 102400);
    float*  sscore = (float*)(ws + 128000);
    float4* sbox   = (float4*)(ws + 153600);

    k_one<<<NBLK, 256, 0, stream>>>(pred, out, boffw, sidx, sscore, sbox);
}

// Round 10
// 66.398 us; speedup vs baseline: 1.0750x; 1.0750x over previous
//
#include <hip/hip_runtime.h>
#include <stdint.h>

#define NBOX 6400
#define GRIDW 80
#define NC 20
#define NBLK 100   // NBOX / 64

__device__ __forceinline__ float sigmoidf(float x) { return 1.0f / (1.0f + expf(-x)); }

// Full per-box decode, exact reference formulas (outputs must be bit-faithful).
__device__ __forceinline__ void decode_one(const float* __restrict__ p, int n,
        float4* box, float* score, int* cls) {
    float conf = sigmoidf(p[0]);
    float c[NC];
    float m = -INFINITY;
    #pragma unroll
    for (int j = 0; j < NC; j++) { c[j] = p[1 + j]; m = fmaxf(m, c[j]); }
    float sum = 0.f;
    #pragma unroll
    for (int j = 0; j < NC; j++) { c[j] = expf(c[j] - m); sum += c[j]; }
    float best = -INFINITY; int bi = 0;
    #pragma unroll
    for (int j = 0; j < NC; j++) {
        float s = (c[j] / sum) * conf;        // softmax*conf, first-max argmax
        if (s > best) { best = s; bi = j; }
    }
    float gx = (float)(n / GRIDW);            // meshgrid 'ij': n = gx*80 + gy
    float gy = (float)(n % GRIDW);
    float cx = (gx + sigmoidf(p[21])) * 32.0f;
    float cy = (gy + sigmoidf(p[22])) * 32.0f;
    float w = expf(p[23]);
    float h = expf(p[24]);
    box->x = fminf(fmaxf((cx - w * 0.5f) / 2560.0f, 0.0f), 1.0f);
    box->y = fminf(fmaxf((cy - h * 0.5f) / 2560.0f, 0.0f), 1.0f);
    box->z = fminf(fmaxf((cx + w * 0.5f) / 2560.0f, 0.0f), 1.0f);
    box->w = fminf(fmaxf((cy + h * 0.5f) / 2560.0f, 0.0f), 1.0f);
    *score = best;
    *cls = bi;
}

// Dispatch 1 (100 blocks x 64 — one chunk per block, 100 CUs for latency):
// decode + write all outputs (keep==valid provisional, exact when no
// suppressing pair exists) + per-chunk bbox (wave reduce) + valid ballot;
// zero-init flag/done.
__global__ __launch_bounds__(64) void k_decode(const float* __restrict__ pred,
        float* __restrict__ out, float4* __restrict__ boff,
        float* __restrict__ score_ws, float4* __restrict__ blkbb,
        uint64_t* __restrict__ validw, uint32_t* __restrict__ flag,
        uint32_t* __restrict__ done) {
    int t = threadIdx.x;
    int n = blockIdx.x * 64 + t;
    if (n == 0) { flag[0] = 0u; done[0] = 0u; }   // ws is poisoned each call
    float4 bx; float s; int cls;
    decode_one(pred + (size_t)n * 25, n, &bx, &s, &cls);
    ((float4*)out)[n] = bx;               // output 0: boxes
    out[32000 + n] = (float)cls;          // output 2: class_idx
    bool valid = s >= 0.01f;
    out[25600 + n] = valid ? s : 0.0f;    // output 1: scores*keep (fast path)
    out[38400 + n] = valid ? 1.0f : 0.0f; // output 3: keep (fast path)
    score_ws[n] = s;
    float off = 2.0f * (float)cls;        // class-offset trick (matches ref order)
    boff[n] = make_float4(bx.x + off, bx.y + off, bx.z + off, bx.w + off);

    // chunk bbox over valid boxes (un-offset geometry; conservative screen —
    // cross-class pairs are handled exactly by the offset boxes in k_pairs)
    float x1 = valid ? bx.x :  INFINITY;
    float y1 = valid ? bx.y :  INFINITY;
    float x2 = valid ? bx.z : -INFINITY;
    float y2 = valid ? bx.w : -INFINITY;
    #pragma unroll
    for (int d = 1; d < 64; d <<= 1) {
        x1 = fminf(x1, __shfl_xor(x1, d));
        y1 = fminf(y1, __shfl_xor(y1, d));
        x2 = fmaxf(x2, __shfl_xor(x2, d));
        y2 = fmaxf(y2, __shfl_xor(y2, d));
    }
    uint64_t vb = __ballot(valid);
    if (t == 0) {
        blkbb[blockIdx.x] = make_float4(x1, y1, x2, y2);
        validw[blockIdx.x] = vb;
    }
}

// Dispatch 2 (100 x 256): block owns row-block bi. Lane-parallel bbox screen
// over bj>=bi; per surviving bj: stage 64 boxes in LDS, 4 waves each test a
// 16-column slice fully unrolled & branch-free (LDS uniform-address broadcast,
// no shfl chains). Any possible IoU>0.5 pair -> flag. Last finishing block
// (done-counter, no polling) runs the exact NMS fallback iff flag set
// (never on this input).
__global__ __launch_bounds__(256) void k_pairs(const float4* __restrict__ boff,
        const float4* __restrict__ blkbb, const uint64_t* __restrict__ validw,
        const float* __restrict__ score, uint32_t* __restrict__ flag,
        uint32_t* __restrict__ done, int* __restrict__ sidx,
        float* __restrict__ sscore, float4* __restrict__ sbox,
        float* __restrict__ out) {
    __shared__ float4 cblds[64];          // staged column boxes (offset coords)
    __shared__ uint64_t klds[NBOX];       // 51.2 KB, fallback path only
    __shared__ uint32_t keepb[NBOX / 32]; // fallback path only
    __shared__ uint32_t lastf;
    int t = threadIdx.x;
    int w = t >> 6, l = t & 63;
    int bi = blockIdx.x;

    float4 ra = blkbb[bi];
    uint64_t rowvalid = validw[bi];
    const float M = 1e-5f;
    // screen (identical ballots in every wave -> uniform survivor list)
    uint64_t surv_lo = 0ull, surv_hi = 0ull;
    if (rowvalid != 0ull) {
        bool ov = false;
        int bj = bi + l;
        if (bj < NBLK) {
            float4 ca = blkbb[bj];
            ov = (fminf(ra.z, ca.z) + M >= fmaxf(ra.x, ca.x)) &&
                 (fminf(ra.w, ca.w) + M >= fmaxf(ra.y, ca.y));
        }
        surv_lo = __ballot(ov);
        ov = false;
        bj = bi + 64 + l;
        if (bj < NBLK) {
            float4 ca = blkbb[bj];
            ov = (fminf(ra.z, ca.z) + M >= fmaxf(ra.x, ca.x)) &&
                 (fminf(ra.w, ca.w) + M >= fmaxf(ra.y, ca.y));
        }
        surv_hi = __ballot(ov);
    }

    int i = bi * 64 + l;                  // each wave covers all 64 rows
    float4 rb = boff[i];
    float areai = (rb.z - rb.x) * (rb.w - rb.y);
    bool rv = (rowvalid >> l) & 1ull;
    bool hit = false;
    while ((surv_lo | surv_hi) != 0ull) { // uniform across block
        int d;
        if (surv_lo) { d = __ffsll((unsigned long long)surv_lo) - 1; surv_lo &= surv_lo - 1; }
        else { d = 64 + __ffsll((unsigned long long)surv_hi) - 1; surv_hi &= surv_hi - 1; }
        int bj = bi + d;
        uint64_t colvalid = validw[bj];
        __syncthreads();
        if (t < 64) cblds[t] = boff[bj * 64 + t];
        __syncthreads();
        if (colvalid != 0ull) {
            #pragma unroll
            for (int k2 = 0; k2 < 16; k2++) {
                int s2 = w * 16 + k2;                 // wave-uniform column
                float4 b = cblds[s2];                 // LDS broadcast read
                bool ok = rv && ((colvalid >> s2) & 1ull) &&
                          !(bi == bj && s2 <= l);     // unordered pairs once
                float xx1 = fmaxf(rb.x, b.x);
                float yy1 = fmaxf(rb.y, b.y);
                float xx2 = fminf(rb.z, b.z);
                float yy2 = fminf(rb.w, b.w);
                float ww = fmaxf(1e-28f, xx2 - xx1);  // EPS exactly as reference
                float hh = fmaxf(1e-28f, yy2 - yy1);
                float inter = ww * hh;
                float areaj = (b.z - b.x) * (b.w - b.y);
                // iou>0.5 <=> 3*inter > areai+areaj (denom>0); margin covers f32
                // rounding; also triggers on degenerate denom<=0 corners.
                hit |= ok && (3.0f * inter >= 0.9995f * (areai + areaj));
            }
        }
    }
    if (__ballot(hit) != 0ull && l == 0) atomicOr(flag, 1u);

    // ---- last-block-done (single atomic, no polling): fallback iff hit ----
    __syncthreads();
    __threadfence();
    if (t == 0) lastf = (atomicAdd(done, 1u) == NBLK - 1) ? 1u : 0u;
    __syncthreads();
    if (!lastf) return;
    if (t == 0) lastf = atomicOr(flag, 0u);
    __syncthreads();
    if (!lastf) return;

    // ---- exact reference NMS (rank sort + sequential greedy), 256 threads ----
    for (int n = t; n < NBOX; n += 256)
        klds[n] = (((uint64_t)(~__float_as_uint(score[n]))) << 32) | (uint32_t)n;
    __syncthreads();
    for (int n = t; n < NBOX; n += 256) {
        uint64_t mk = klds[n];
        int r = 0;
        for (int j = 0; j < NBOX; j++) r += (klds[j] < mk) ? 1 : 0;
        sidx[r] = n;
        sscore[r] = score[n];
        sbox[r] = boff[n];
    }
    __syncthreads();
    for (int w2 = t; w2 < NBOX / 32; w2 += 256) {
        uint32_t v = 0;
        for (int b = 0; b < 32; b++) v |= (sscore[w2 * 32 + b] >= 0.01f) ? (1u << b) : 0u;
        keepb[w2] = v;
    }
    __syncthreads();
    for (int ii = 0; ii < NBOX; ii++) {
        bool kept = (keepb[ii >> 5] >> (ii & 31)) & 1u;   // uniform LDS broadcast
        if (kept) {
            float4 a = sbox[ii];
            float areaa = (a.z - a.x) * (a.w - a.y);
            for (int j = ii + 1 + t; j < NBOX; j += 256) {
                if ((keepb[j >> 5] >> (j & 31)) & 1u) {
                    float4 b = sbox[j];
                    float xx1 = fmaxf(a.x, b.x);
                    float yy1 = fmaxf(a.y, b.y);
                    float xx2 = fminf(a.z, b.z);
                    float yy2 = fminf(a.w, b.w);
                    float ww = fmaxf(1e-28f, xx2 - xx1);
                    float hh = fmaxf(1e-28f, yy2 - yy1);
                    float inter = ww * hh;
                    float areab = (b.z - b.x) * (b.w - b.y);
                    float iou = inter / (areaa + areab - inter);  // exact ref formula
                    if (iou > 0.5f) atomicAnd(&keepb[j >> 5], ~(1u << (j & 31)));
                }
            }
        }
        __syncthreads();
    }
    for (int r = t; r < NBOX; r += 256) {
        int orig = sidx[r];
        uint32_t kb = (keepb[r >> 5] >> (r & 31)) & 1u;
        out[38400 + orig] = (float)kb;
        out[25600 + orig] = kb ? sscore[r] : 0.0f;
    }
}

extern "C" void kernel_launch(void* const* d_in, const int* in_sizes, int n_in,
                              void* d_out, int out_size, void* d_ws, size_t ws_size,
                              hipStream_t stream) {
    const float* pred = (const float*)d_in[0];
    float* out = (float*)d_out;
    char* ws = (char*)d_ws;
    float4*   boff   = (float4*)(ws + 0);        // 6400 f4  (102400 B)
    float*    score  = (float*)(ws + 102400);    // 6400 f32
    float4*   blkbb  = (float4*)(ws + 128000);   // 100 f4 chunk bboxes
    uint64_t* validw = (uint64_t*)(ws + 129600); // 100 u64 valid ballots
    uint32_t* flag   = (uint32_t*)(ws + 130432); // 1 u32
    uint32_t* done   = (uint32_t*)(ws + 130436); // 1 u32
    int*      sidx   = (int*)(ws + 131072);      // slow path only
    float*    sscore = (float*)(ws + 156672);    // slow path only
    float4*   sbox   = (float4*)(ws + 182272);   // slow path only

    k_decode<<<NBLK, 64, 0, stream>>>(pred, out, boff, score, blkbb, validw, flag, done);
    k_pairs<<<NBLK, 256, 0, stream>>>(boff, blkbb, validw, score, flag, done,
                                      sidx, sscore, sbox, out);
}